// Round 5
// baseline (1020.331 us; speedup 1.0000x reference)
//
#include <hip/hip_runtime.h>
#include <stdint.h>

#define HW (512 * 512)
#define NBINS 256
#define NB 128
#define CHUNKS 32          // 16 rows per chunk
#define CPX4 2048          // float4s (= 8192 pixels) per chunk

// ---------------- workspace layout (bytes) ----------------
// 0      : counts[256]   int   (per-bin totals, batch-independent)
// 1024   : S1[128][256]  float
// 132096 : S2[128][256]  float
// total  : 263168

// ---- per-bin pixel counts (bins only); direct global int atomics ----
// 256 blocks x 256 threads, one int4 per thread.
__global__ __launch_bounds__(256) void countk(const int* __restrict__ bins,
                                              int* __restrict__ counts) {
    const int i = blockIdx.x * 256 + threadIdx.x;       // int4 index
    const int4 bb = ((const int4*)bins)[i];
    const int arr[4] = {bb.x, bb.y, bb.z, bb.w};
    int cb = -1, cnt = 0;
    #pragma unroll
    for (int m = 0; m < 4; ++m) {
        const int vb = (arr[m] > 3 && arr[m] < NBINS) ? arr[m] : -1;
        if (vb != cb) {
            if (cb >= 0) atomicAdd(&counts[cb], cnt);
            cb = vb; cnt = 0;
        }
        cnt += (vb >= 0) ? 1 : 0;
    }
    if (cb >= 0) atomicAdd(&counts[cb], cnt);
}

// ---- main pass: pure streaming; run-merged fire-and-forget global atomics ----
// Rounds 1/3/4 proved the cost was ~190 cy per *wave-level LDS-atomic instr*
// (invariant to CAS-vs-native, collisions, lane count). So: no LDS at all.
// Flush register-merged runs straight to S1/S2 via non-returning
// global_atomic_add_f32 (issue ~4 cy, no wait, served by L2/LLC).
__global__ __launch_bounds__(256) void pass(const float* __restrict__ parts,
                                            const float* __restrict__ projs,
                                            const int* __restrict__ bins,
                                            float* __restrict__ S1,
                                            float* __restrict__ S2) {
    const int t = threadIdx.x;
    const int chunk = blockIdx.x;
    const int b = blockIdx.y;

    float* __restrict__ s1b = S1 + b * NBINS;
    float* __restrict__ s2b = S2 + b * NBINS;

    const float4* __restrict__ P4 = (const float4*)(parts + (size_t)b * HW) + chunk * CPX4;
    const float4* __restrict__ Q4 = (const float4*)(projs + (size_t)b * HW) + chunk * CPX4;
    const int4*   __restrict__ B4 = (const int4*)bins + chunk * CPX4;

    int   cb = -1;                 // current run bin (carried across quads)
    float a1 = 0.f, a2 = 0.f;      // run accumulators

    #pragma unroll 4
    for (int g = 0; g < 8; ++g) {
        const int idx = g * 256 + t;
        const float4 p = P4[idx];
        const float4 q = Q4[idx];
        const int4  bb = B4[idx];
        const int   barr[4] = {bb.x, bb.y, bb.z, bb.w};
        const float narr[4] = {p.x - q.x, p.y - q.y, p.z - q.z, p.w - q.w};
        #pragma unroll
        for (int m = 0; m < 4; ++m) {
            const int vb = (barr[m] > 3 && barr[m] < NBINS) ? barr[m] : -1;
            if (vb != cb) {
                if (cb >= 0) {
                    unsafeAtomicAdd(&s1b[cb], a1);
                    unsafeAtomicAdd(&s2b[cb], a2);
                }
                cb = vb; a1 = 0.f; a2 = 0.f;
            }
            if (vb >= 0) { const float n = narr[m]; a1 += fabsf(n); a2 += n * n; }
        }
    }
    if (cb >= 0) {
        unsafeAtomicAdd(&s1b[cb], a1);
        unsafeAtomicAdd(&s2b[cb], a2);
    }
}

// ---- finalize: per-batch closed-form sum over bins ----
__global__ __launch_bounds__(256) void finalize(const float* __restrict__ S1,
                                                const float* __restrict__ S2,
                                                const int* __restrict__ counts,
                                                float* __restrict__ out) {
    const int b = blockIdx.x;
    const int t = threadIdx.x;
    float contrib = 0.f;
    if (t > 3) {   // valid bins 4..255
        float c = (float)counts[t];
        float s1 = S1[b * NBINS + t];
        float s2 = S2[b * NBINS + t];
        float mean = s1 / fmaxf(c, 1.f);
        float ssq = fmaxf(s2 - mean * s1, 0.f);          // = sum (a - mean)^2
        float var = ssq / fmaxf(c - 1.f, 1.f);
        contrib = -0.5f * s2 / var - c * logf(6.283185307179586f * var);
    }
    #pragma unroll
    for (int off = 32; off > 0; off >>= 1) contrib += __shfl_down(contrib, off, 64);
    __shared__ float w[4];
    if ((t & 63) == 0) w[t >> 6] = contrib;
    __syncthreads();
    if (t == 0) out[b] = w[0] + w[1] + w[2] + w[3];
}

extern "C" void kernel_launch(void* const* d_in, const int* in_sizes, int n_in,
                              void* d_out, int out_size, void* d_ws, size_t ws_size,
                              hipStream_t stream) {
    const float* parts = (const float*)d_in[0];
    const float* projs = (const float*)d_in[1];
    const int* bins    = (const int*)d_in[2];
    float* out = (float*)d_out;

    char* ws = (char*)d_ws;
    int*   counts = (int*)(ws + 0);
    float* S1     = (float*)(ws + 1024);
    float* S2     = (float*)(ws + 132096);

    hipMemsetAsync(d_ws, 0, 263168, stream);
    countk  <<<256, 256, 0, stream>>>(bins, counts);         // 1024 px / block
    pass    <<<dim3(CHUNKS, NB), 256, 0, stream>>>(parts, projs, bins, S1, S2);
    finalize<<<NB, 256, 0, stream>>>(S1, S2, counts, out);
}

// Round 6
// 1002.041 us; speedup vs baseline: 1.0183x; 1.0183x over previous
//
#include <hip/hip_runtime.h>
#include <hip/hip_cooperative_groups.h>
#include <stdint.h>

namespace cg = cooperative_groups;

#define HW (512 * 512)
#define NBINS 256
#define NB 128
#define PAD 1664          // per-bin slot stride; max ring count ~= 2*pi*255 ~ 1602
#define CSTR 16           // cursor padding stride in ints (64 B) -> per-address contention only
#define GRID_COOP 2048    // 4 blocks/CU x 256 CUs -> co-resident for cooperative launch

// ---------------- workspace layout (bytes) ----------------
// 0       cursor[256*16] int   (memset 16 KB; cursor[k*16] ends as count of bin k)
// 16384   S1[128][256]  float  (written unconditionally by phase B -> no memset)
// 147456  S2[128][256]  float
// 278528  perm[256][1664] int  (pixel indices bucketed by bin)
// total   1982464

// ---- phase A: bucket pixel indices by bin (runs on blocks 0..255) ----
// LDS atomics here total 262k lane-ops (~3 cy each CU-wide = ~1.3 us) -- cheap at
// this count; the round-1..4 lesson was about 67M of them, not 262k.
__device__ __forceinline__ void phaseA(const int* __restrict__ bins,
                                       int* __restrict__ cursor,
                                       int* __restrict__ perm,
                                       int blk, int t, int* hist, int* loff) {
    hist[t] = 0;
    __syncthreads();
    const int4 bb = ((const int4*)bins)[blk * 256 + t];
    const int barr[4] = {bb.x, bb.y, bb.z, bb.w};
    int vb[4];
    #pragma unroll
    for (int m = 0; m < 4; ++m) {
        vb[m] = (barr[m] > 3 && barr[m] < NBINS) ? barr[m] : -1;
        if (vb[m] >= 0) atomicAdd(&hist[vb[m]], 1);
    }
    __syncthreads();
    const int h = hist[t];
    const int base = (h > 0) ? atomicAdd(&cursor[t * CSTR], h) : 0;  // <=256 RMW/address
    __syncthreads();
    hist[t] = base;          // reuse hist[] as per-bin global base
    loff[t] = 0;
    __syncthreads();
    #pragma unroll
    for (int m = 0; m < 4; ++m) {
        if (vb[m] >= 0) {
            const int pos = hist[vb[m]] + atomicAdd(&loff[vb[m]], 1);
            const int px = (blk * 256 + t) * 4 + m;
            if (pos < PAD)
                __hip_atomic_store(&perm[vb[m] * PAD + pos], px,
                                   __ATOMIC_RELAXED, __HIP_MEMORY_SCOPE_AGENT);
        }
    }
}

// ---- phase B tile: one (bin, batch); whole block same bin -> atomic-free ----
__device__ __forceinline__ void tileB(const float* __restrict__ Pb,
                                      const float* __restrict__ Qb,
                                      const int* __restrict__ pb, int count, int t,
                                      float* r1, float* r2,
                                      float* S1e, float* S2e) {
    float a1 = 0.f, a2 = 0.f;
    #pragma unroll
    for (int kk = 0; kk < 7; ++kk) {             // 7*256 = 1792 >= PAD
        const int e = t + kk * 256;
        if (e < count) {
            const int px = pb[e];
            const float n = Pb[px] - Qb[px];
            a1 += fabsf(n);
            a2 += n * n;
        }
    }
    #pragma unroll
    for (int off = 32; off > 0; off >>= 1) {
        a1 += __shfl_down(a1, off, 64);
        a2 += __shfl_down(a2, off, 64);
    }
    if ((t & 63) == 0) { r1[t >> 6] = a1; r2[t >> 6] = a2; }
    __syncthreads();
    if (t == 0) {
        __hip_atomic_store(S1e, r1[0] + r1[1] + r1[2] + r1[3],
                           __ATOMIC_RELAXED, __HIP_MEMORY_SCOPE_AGENT);
        __hip_atomic_store(S2e, r2[0] + r2[1] + r2[2] + r2[3],
                           __ATOMIC_RELAXED, __HIP_MEMORY_SCOPE_AGENT);
    }
    __syncthreads();                              // r1/r2 reused next tile
}

// ---- phase C: finalize one batch (runs on blocks 0..127) ----
__device__ __forceinline__ void phaseC(const float* __restrict__ S1,
                                       const float* __restrict__ S2,
                                       const int* __restrict__ cursor,
                                       float* __restrict__ out,
                                       int b, int t, float* w) {
    float contrib = 0.f;
    if (t > 3) {   // valid bins 4..255
        const float c  = (float)cursor[t * CSTR];
        const float s1 = S1[b * NBINS + t];
        const float s2 = S2[b * NBINS + t];
        const float mean = s1 / fmaxf(c, 1.f);
        const float ssq  = fmaxf(s2 - mean * s1, 0.f);
        const float var  = ssq / fmaxf(c - 1.f, 1.f);
        contrib = -0.5f * s2 / var - c * logf(6.283185307179586f * var);
    }
    #pragma unroll
    for (int off = 32; off > 0; off >>= 1) contrib += __shfl_down(contrib, off, 64);
    if ((t & 63) == 0) w[t >> 6] = contrib;
    __syncthreads();
    if (t == 0) out[b] = w[0] + w[1] + w[2] + w[3];
}

// ---- fused cooperative kernel: bucket -> grid.sync -> tiles -> grid.sync -> finalize
extern "C" __global__ __launch_bounds__(256, 4) void fused(
        const float* __restrict__ parts, const float* __restrict__ projs,
        const int* __restrict__ bins, int* __restrict__ cursor,
        float* __restrict__ S1, float* __restrict__ S2,
        int* __restrict__ perm, float* __restrict__ out) {
    __shared__ int sh[512];
    cg::grid_group g = cg::this_grid();
    const int t = threadIdx.x;
    const int blk = blockIdx.x;

    if (blk < 256) phaseA(bins, cursor, perm, blk, t, sh, sh + 256);
    g.sync();

    {   // 2048 blocks = (xcd 0..7) x (bin 0..255); each does 16 batches of its xcd
        const int xcd = blk & 7;
        const int bin = blk >> 3;
        const int count = cursor[bin * CSTR];
        const int* pb = perm + bin * PAD;
        float* r1 = (float*)sh;
        float* r2 = (float*)(sh + 4);
        for (int k = 0; k < 16; ++k) {
            const int b = xcd + (k << 3);         // batch pinned to this XCD's L2
            tileB(parts + (size_t)b * HW, projs + (size_t)b * HW, pb, count, t,
                  r1, r2, &S1[b * NBINS + bin], &S2[b * NBINS + bin]);
        }
    }
    g.sync();

    if (blk < NB) phaseC(S1, S2, cursor, out, blk, t, (float*)sh);
}

// ---- fallback path (non-cooperative), used only if coop enqueue fails ----
__global__ __launch_bounds__(256) void sA(const int* __restrict__ bins,
                                          int* __restrict__ cursor,
                                          int* __restrict__ perm) {
    __shared__ int sh[512];
    phaseA(bins, cursor, perm, blockIdx.x, threadIdx.x, sh, sh + 256);
}
__global__ __launch_bounds__(256) void sB(const float* __restrict__ parts,
                                          const float* __restrict__ projs,
                                          const int* __restrict__ cursor,
                                          const int* __restrict__ perm,
                                          float* __restrict__ S1,
                                          float* __restrict__ S2) {
    __shared__ int sh[8];
    const int blk = blockIdx.x;                   // 32768 flat
    const int xcd = blk & 7;
    const int bin = (blk >> 3) & 255;
    const int b = xcd + ((blk >> 11) << 3);
    const int count = cursor[bin * CSTR];
    tileB(parts + (size_t)b * HW, projs + (size_t)b * HW, perm + bin * PAD, count,
          threadIdx.x, (float*)sh, (float*)(sh + 4),
          &S1[b * NBINS + bin], &S2[b * NBINS + bin]);
}
__global__ __launch_bounds__(256) void sC(const float* __restrict__ S1,
                                          const float* __restrict__ S2,
                                          const int* __restrict__ cursor,
                                          float* __restrict__ out) {
    __shared__ float w[4];
    phaseC(S1, S2, cursor, out, blockIdx.x, threadIdx.x, w);
}

extern "C" void kernel_launch(void* const* d_in, const int* in_sizes, int n_in,
                              void* d_out, int out_size, void* d_ws, size_t ws_size,
                              hipStream_t stream) {
    const float* parts = (const float*)d_in[0];
    const float* projs = (const float*)d_in[1];
    const int* bins    = (const int*)d_in[2];
    float* out = (float*)d_out;

    char* ws = (char*)d_ws;
    int*   cursor = (int*)(ws + 0);
    float* S1     = (float*)(ws + 16384);
    float* S2     = (float*)(ws + 147456);
    int*   perm   = (int*)(ws + 278528);

    hipMemsetAsync(d_ws, 0, 16384, stream);   // cursor only; S1/S2 written unconditionally

    void* args[] = {(void*)&parts, (void*)&projs, (void*)&bins, (void*)&cursor,
                    (void*)&S1, (void*)&S2, (void*)&perm, (void*)&out};
    hipError_t e = hipLaunchCooperativeKernel(reinterpret_cast<void*>(fused),
                                              dim3(GRID_COOP), dim3(256),
                                              args, 0, stream);
    if (e != hipSuccess) {                     // insurance: classic 3-dispatch path
        sA<<<256,   256, 0, stream>>>(bins, cursor, perm);
        sB<<<32768, 256, 0, stream>>>(parts, projs, cursor, perm, S1, S2);
        sC<<<NB,    256, 0, stream>>>(S1, S2, cursor, out);
    }
}

// Round 7
// 298.590 us; speedup vs baseline: 3.4172x; 3.3559x over previous
//
#include <hip/hip_runtime.h>
#include <stdint.h>

#define HW (512 * 512)
#define NBINS 256
#define NB 128
#define NTILES 64          // 8x8 tiles of 64x64
#define TPX 4096           // pixels per tile

// ---------------- workspace layout (bytes) ----------------
// 0      : tileCount[64]   int
// 512    : counts[256]     int   (per-bin totals, batch-independent)
// 4096   : S1[128][256]    float
// 135168 : S2[128][256]    float
// 266240 : perm[64][4096]  int packed (bin<<12 | local)

// Native fire-and-forget LDS float atomic (round-4 verified). Plain atomicAdd
// on __shared__ float is a CAS loop (2+ LDS lane-ops); ds_add_f32 is 1.
__device__ __forceinline__ void lds_fadd(uint32_t byte_off, float v) {
    asm volatile("ds_add_f32 %0, %1" :: "v"(byte_off), "v"(v));
}

// ---- kernel 1 (once per launch): counting-sort each tile's pixels by bin ----
// Verbatim from the 304us-session kernel (verified).
__global__ __launch_bounds__(256) void tilesort(const int* __restrict__ bins,
                                                int* __restrict__ perm,
                                                int* __restrict__ tileCount,
                                                int* __restrict__ counts) {
    __shared__ int hist[NBINS];
    __shared__ int sc[NBINS];
    __shared__ int cursor[NBINS];
    const int t = threadIdx.x;
    const int tile = blockIdx.x;
    const int trow = tile >> 3, tcol = tile & 7;
    hist[t] = 0;
    __syncthreads();

    int myBins[16];
    #pragma unroll
    for (int k = 0; k < 4; ++k) {
        int row = (t >> 4) + k * 16;
        int col4 = t & 15;
        int4 v = *(const int4*)&bins[(trow * 64 + row) * 512 + tcol * 64 + col4 * 4];
        int bb[4] = {v.x, v.y, v.z, v.w};
        #pragma unroll
        for (int m = 0; m < 4; ++m) {
            myBins[k * 4 + m] = bb[m];
            if (bb[m] > 3 && bb[m] < NBINS) atomicAdd(&hist[bb[m]], 1);
        }
    }
    __syncthreads();
    sc[t] = hist[t];
    __syncthreads();
    for (int off = 1; off < 256; off <<= 1) {
        int x = (t >= off) ? sc[t - off] : 0;
        __syncthreads();
        sc[t] += x;
        __syncthreads();
    }
    cursor[t] = sc[t] - hist[t];     // exclusive prefix
    if (t == 255) tileCount[tile] = sc[255];
    if (hist[t]) atomicAdd(&counts[t], hist[t]);
    __syncthreads();

    #pragma unroll
    for (int k = 0; k < 4; ++k) {
        int row = (t >> 4) + k * 16;
        int col4 = t & 15;
        #pragma unroll
        for (int m = 0; m < 4; ++m) {
            int bn = myBins[k * 4 + m];
            if (bn > 3 && bn < NBINS) {
                int local = row * 64 + col4 * 4 + m;
                int pos = atomicAdd(&cursor[bn], 1);
                perm[tile * TPX + pos] = (bn << 12) | local;
            }
        }
    }
}

// ---- kernel 2: main pass ----
// vs the 304us session: stage n=P-Q (16KB LDS, not 34.8KB P+Q) -> 8 blocks/CU
// instead of 4 (stage latency now hidden); 1 ds_read per gathered pixel
// instead of 2; run flushes via native ds_add_f32 instead of CAS atomicAdd.
__global__ __launch_bounds__(256) void pass(const float* __restrict__ parts,
                                            const float* __restrict__ projs,
                                            const int* __restrict__ perm,
                                            const int* __restrict__ tileCount,
                                            float* __restrict__ S1,
                                            float* __restrict__ S2) {
    __shared__ float sN[TPX];
    __shared__ float h1[NBINS], h2[NBINS];
    const int t = threadIdx.x;
    const int tile = blockIdx.x;
    const int b = blockIdx.y;
    const int trow = tile >> 3, tcol = tile & 7;
    h1[t] = 0.f; h2[t] = 0.f;

    const float* __restrict__ P = parts + (size_t)b * HW;
    const float* __restrict__ Q = projs + (size_t)b * HW;

    // hoisted perm loads (coalesced int4; overlap with stage latency).
    // Entries beyond count are stale garbage but guarded below.
    const int count = tileCount[tile];
    const int e0 = t * 16;
    int4 pe[4];
    {
        const int4* p4 = (const int4*)(perm + tile * TPX + e0);
        #pragma unroll
        for (int g = 0; g < 4; ++g) pe[g] = p4[g];
    }

    // stage n = P - Q: coalesced float4 reads, XOR-swizzled LDS slots so
    // vertical arcs (constant col) spread across banks in the gather phase
    #pragma unroll
    for (int k = 0; k < 4; ++k) {
        int row = (t >> 4) + k * 16;
        int col4 = t & 15;
        const float4 p = *(const float4*)&P[(trow * 64 + row) * 512 + tcol * 64 + col4 * 4];
        const float4 q = *(const float4*)&Q[(trow * 64 + row) * 512 + tcol * 64 + col4 * 4];
        int x = row & 31;
        int rb = row * 64;
        sN[rb + ((col4 * 4 + 0) ^ x)] = p.x - q.x;
        sN[rb + ((col4 * 4 + 1) ^ x)] = p.y - q.y;
        sN[rb + ((col4 * 4 + 2) ^ x)] = p.z - q.z;
        sN[rb + ((col4 * 4 + 3) ^ x)] = p.w - q.w;
    }
    __syncthreads();

    const uint32_t h1b = (uint32_t)(uintptr_t)&h1[0];
    const uint32_t h2b = (uint32_t)(uintptr_t)&h2[0];
    float a1 = 0.f, a2 = 0.f;
    int curBin = -1;

    if (e0 < count) {
        #pragma unroll
        for (int g = 0; g < 4; ++g) {
            int ee[4] = {pe[g].x, pe[g].y, pe[g].z, pe[g].w};
            #pragma unroll
            for (int k2 = 0; k2 < 4; ++k2) {
                int idx = e0 + g * 4 + k2;
                if (idx < count) {
                    int e = ee[k2];
                    int bn = e >> 12;
                    int local = e & 4095;
                    int slot = local ^ ((local >> 6) & 31);
                    float n = sN[slot];
                    if (bn != curBin) {
                        if (curBin >= 0) {
                            lds_fadd(h1b + (uint32_t)curBin * 4u, a1);
                            lds_fadd(h2b + (uint32_t)curBin * 4u, a2);
                        }
                        curBin = bn; a1 = 0.f; a2 = 0.f;
                    }
                    a1 += fabsf(n);
                    a2 += n * n;
                }
            }
        }
        if (curBin >= 0) {
            lds_fadd(h1b + (uint32_t)curBin * 4u, a1);
            lds_fadd(h2b + (uint32_t)curBin * 4u, a2);
        }
    }
    // drain asm DS atomics (compiler's waitcnt model can't see them)
    asm volatile("s_waitcnt lgkmcnt(0)" ::: "memory");
    __syncthreads();
    if (h1[t] != 0.f) unsafeAtomicAdd(&S1[b * NBINS + t], h1[t]);
    if (h2[t] != 0.f) unsafeAtomicAdd(&S2[b * NBINS + t], h2[t]);
}

// ---- finalize: per-batch closed-form sum over bins (verbatim, verified) ----
__global__ __launch_bounds__(256) void finalize(const float* __restrict__ S1,
                                                const float* __restrict__ S2,
                                                const int* __restrict__ counts,
                                                float* __restrict__ out) {
    const int b = blockIdx.x;
    const int t = threadIdx.x;
    float contrib = 0.f;
    if (t > 3) {   // valid bins 4..255
        float c = (float)counts[t];
        float s1 = S1[b * NBINS + t];
        float s2 = S2[b * NBINS + t];
        float mean = s1 / fmaxf(c, 1.f);
        float ssq = fmaxf(s2 - mean * s1, 0.f);          // = sum (a - mean)^2
        float var = ssq / fmaxf(c - 1.f, 1.f);
        contrib = -0.5f * s2 / var - c * logf(6.283185307179586f * var);
    }
    #pragma unroll
    for (int off = 32; off > 0; off >>= 1) contrib += __shfl_down(contrib, off, 64);
    __shared__ float w[4];
    if ((t & 63) == 0) w[t >> 6] = contrib;
    __syncthreads();
    if (t == 0) out[b] = w[0] + w[1] + w[2] + w[3];
}

extern "C" void kernel_launch(void* const* d_in, const int* in_sizes, int n_in,
                              void* d_out, int out_size, void* d_ws, size_t ws_size,
                              hipStream_t stream) {
    const float* parts = (const float*)d_in[0];
    const float* projs = (const float*)d_in[1];
    const int* bins    = (const int*)d_in[2];
    float* out = (float*)d_out;

    char* ws = (char*)d_ws;
    int*   tileCount = (int*)(ws + 0);
    int*   counts    = (int*)(ws + 512);
    float* S1        = (float*)(ws + 4096);
    float* S2        = (float*)(ws + 135168);
    int*   perm      = (int*)(ws + 266240);

    hipMemsetAsync(d_ws, 0, 266240, stream);   // counts + S1 + S2
    tilesort<<<NTILES, 256, 0, stream>>>(bins, perm, tileCount, counts);
    pass    <<<dim3(NTILES, NB), 256, 0, stream>>>(parts, projs, perm, tileCount, S1, S2);
    finalize<<<NB, 256, 0, stream>>>(S1, S2, counts, out);
}

// Round 8
// 293.351 us; speedup vs baseline: 3.4782x; 1.0179x over previous
//
#include <hip/hip_runtime.h>
#include <stdint.h>

#define HW (512 * 512)
#define NBINS 256
#define NB 128
#define NTILES 64          // 8x8 tiles of 64x64
#define TPX 4096           // pixels per tile

// ---------------- workspace layout (bytes) ----------------
// 0      : tileCount[64]   int
// 512    : counts[256]     int   (per-bin totals, batch-independent)
// 4096   : S1[128][256]    float
// 135168 : S2[128][256]    float
// 266240 : perm[64][4096]  int packed (bin<<12 | local)

// ---- kernel 1 (once per launch): counting-sort each tile's pixels by bin ----
// Verbatim (verified). Int LDS atomics here: 64 blocks only, not hot.
__global__ __launch_bounds__(256) void tilesort(const int* __restrict__ bins,
                                                int* __restrict__ perm,
                                                int* __restrict__ tileCount,
                                                int* __restrict__ counts) {
    __shared__ int hist[NBINS];
    __shared__ int sc[NBINS];
    __shared__ int cursor[NBINS];
    const int t = threadIdx.x;
    const int tile = blockIdx.x;
    const int trow = tile >> 3, tcol = tile & 7;
    hist[t] = 0;
    __syncthreads();

    int myBins[16];
    #pragma unroll
    for (int k = 0; k < 4; ++k) {
        int row = (t >> 4) + k * 16;
        int col4 = t & 15;
        int4 v = *(const int4*)&bins[(trow * 64 + row) * 512 + tcol * 64 + col4 * 4];
        int bb[4] = {v.x, v.y, v.z, v.w};
        #pragma unroll
        for (int m = 0; m < 4; ++m) {
            myBins[k * 4 + m] = bb[m];
            if (bb[m] > 3 && bb[m] < NBINS) atomicAdd(&hist[bb[m]], 1);
        }
    }
    __syncthreads();
    sc[t] = hist[t];
    __syncthreads();
    for (int off = 1; off < 256; off <<= 1) {
        int x = (t >= off) ? sc[t - off] : 0;
        __syncthreads();
        sc[t] += x;
        __syncthreads();
    }
    cursor[t] = sc[t] - hist[t];     // exclusive prefix
    if (t == 255) tileCount[tile] = sc[255];
    if (hist[t]) atomicAdd(&counts[t], hist[t]);
    __syncthreads();

    #pragma unroll
    for (int k = 0; k < 4; ++k) {
        int row = (t >> 4) + k * 16;
        int col4 = t & 15;
        #pragma unroll
        for (int m = 0; m < 4; ++m) {
            int bn = myBins[k * 4 + m];
            if (bn > 3 && bn < NBINS) {
                int local = row * 64 + col4 * 4 + m;
                int pos = atomicAdd(&cursor[bn], 1);
                perm[tile * TPX + pos] = (bn << 12) | local;
            }
        }
    }
}

// ---- kernel 2: main pass — ZERO data-path LDS atomics ----
// Rounds 1/3/4/7 model: LDS-atomic wave-instr issue ~190cy, CU-serialized,
// invariant to lanes/latency/collisions -> was ~all of pass's 110us.
// Replacement, enabled by the bin-sort:
//  * per-wave-private histograms h[4][256] -> cross-wave races gone;
//  * in-loop run flushes: plain LDS RMW. Safe: at any flush site, two lanes
//    flushing the same bin would need that bin's contiguous run to contain
//    16t+off-1 and 16t'+off-1 but not 16t+off between them -> impossible,
//    so active lanes' bins are distinct; wave is lockstep -> race-free.
//  * end-of-loop flush (many lanes share a long run's bin): final curBin is
//    non-decreasing across lanes -> 6-step shfl_up segmented scan; only the
//    last lane of each segment RMWs.
__global__ __launch_bounds__(256) void pass(const float* __restrict__ parts,
                                            const float* __restrict__ projs,
                                            const int* __restrict__ perm,
                                            const int* __restrict__ tileCount,
                                            float* __restrict__ S1,
                                            float* __restrict__ S2) {
    __shared__ float sN[TPX];
    __shared__ float h1[4][NBINS], h2[4][NBINS];
    const int t = threadIdx.x;
    const int tile = blockIdx.x;
    const int b = blockIdx.y;
    const int trow = tile >> 3, tcol = tile & 7;
    #pragma unroll
    for (int i = 0; i < 4; ++i) {
        ((float*)h1)[t + i * 256] = 0.f;
        ((float*)h2)[t + i * 256] = 0.f;
    }

    const float* __restrict__ P = parts + (size_t)b * HW;
    const float* __restrict__ Q = projs + (size_t)b * HW;

    // hoisted perm loads (coalesced int4; overlap with stage latency)
    const int count = tileCount[tile];
    const int e0 = t * 16;
    int4 pe[4];
    {
        const int4* p4 = (const int4*)(perm + tile * TPX + e0);
        #pragma unroll
        for (int g = 0; g < 4; ++g) pe[g] = p4[g];
    }

    // stage n = P - Q: coalesced float4 reads, XOR-swizzled LDS slots
    #pragma unroll
    for (int k = 0; k < 4; ++k) {
        int row = (t >> 4) + k * 16;
        int col4 = t & 15;
        const float4 p = *(const float4*)&P[(trow * 64 + row) * 512 + tcol * 64 + col4 * 4];
        const float4 q = *(const float4*)&Q[(trow * 64 + row) * 512 + tcol * 64 + col4 * 4];
        int x = row & 31;
        int rb = row * 64;
        sN[rb + ((col4 * 4 + 0) ^ x)] = p.x - q.x;
        sN[rb + ((col4 * 4 + 1) ^ x)] = p.y - q.y;
        sN[rb + ((col4 * 4 + 2) ^ x)] = p.z - q.z;
        sN[rb + ((col4 * 4 + 3) ^ x)] = p.w - q.w;
    }
    __syncthreads();

    float* __restrict__ h1w = &h1[t >> 6][0];
    float* __restrict__ h2w = &h2[t >> 6][0];
    float a1 = 0.f, a2 = 0.f;
    int curBin = -1;

    if (e0 < count) {
        #pragma unroll
        for (int g = 0; g < 4; ++g) {
            int ee[4] = {pe[g].x, pe[g].y, pe[g].z, pe[g].w};
            #pragma unroll
            for (int k2 = 0; k2 < 4; ++k2) {
                int idx = e0 + g * 4 + k2;
                if (idx < count) {
                    int e = ee[k2];
                    int bn = e >> 12;
                    int local = e & 4095;
                    int slot = local ^ ((local >> 6) & 31);
                    float n = sN[slot];
                    if (bn != curBin) {
                        if (curBin >= 0) {          // plain RMW: bins distinct per site
                            h1w[curBin] += a1;
                            h2w[curBin] += a2;
                        }
                        curBin = bn; a1 = 0.f; a2 = 0.f;
                    }
                    a1 += fabsf(n);
                    a2 += n * n;
                }
            }
        }
    }
    // end-of-loop flush: segmented reduce across the wave (curBin sorted,
    // invalid lanes hold curBin=-1 at the top), then one RMW per segment.
    #pragma unroll
    for (int d = 1; d < 64; d <<= 1) {
        const int   ob = __shfl_up(curBin, d, 64);
        const float o1 = __shfl_up(a1, d, 64);
        const float o2 = __shfl_up(a2, d, 64);
        if ((t & 63) >= d && ob == curBin) { a1 += o1; a2 += o2; }
    }
    const int nb = __shfl_down(curBin, 1, 64);
    if (curBin >= 0 && (((t & 63) == 63) || nb != curBin)) {
        h1w[curBin] += a1;
        h2w[curBin] += a2;
    }
    __syncthreads();

    const float v1 = h1[0][t] + h1[1][t] + h1[2][t] + h1[3][t];
    const float v2 = h2[0][t] + h2[1][t] + h2[2][t] + h2[3][t];
    if (v1 != 0.f) unsafeAtomicAdd(&S1[b * NBINS + t], v1);
    if (v2 != 0.f) unsafeAtomicAdd(&S2[b * NBINS + t], v2);
}

// ---- finalize: per-batch closed-form sum over bins (verbatim, verified) ----
__global__ __launch_bounds__(256) void finalize(const float* __restrict__ S1,
                                                const float* __restrict__ S2,
                                                const int* __restrict__ counts,
                                                float* __restrict__ out) {
    const int b = blockIdx.x;
    const int t = threadIdx.x;
    float contrib = 0.f;
    if (t > 3) {   // valid bins 4..255
        float c = (float)counts[t];
        float s1 = S1[b * NBINS + t];
        float s2 = S2[b * NBINS + t];
        float mean = s1 / fmaxf(c, 1.f);
        float ssq = fmaxf(s2 - mean * s1, 0.f);          // = sum (a - mean)^2
        float var = ssq / fmaxf(c - 1.f, 1.f);
        contrib = -0.5f * s2 / var - c * logf(6.283185307179586f * var);
    }
    #pragma unroll
    for (int off = 32; off > 0; off >>= 1) contrib += __shfl_down(contrib, off, 64);
    __shared__ float w[4];
    if ((t & 63) == 0) w[t >> 6] = contrib;
    __syncthreads();
    if (t == 0) out[b] = w[0] + w[1] + w[2] + w[3];
}

extern "C" void kernel_launch(void* const* d_in, const int* in_sizes, int n_in,
                              void* d_out, int out_size, void* d_ws, size_t ws_size,
                              hipStream_t stream) {
    const float* parts = (const float*)d_in[0];
    const float* projs = (const float*)d_in[1];
    const int* bins    = (const int*)d_in[2];
    float* out = (float*)d_out;

    char* ws = (char*)d_ws;
    int*   tileCount = (int*)(ws + 0);
    int*   counts    = (int*)(ws + 512);
    float* S1        = (float*)(ws + 4096);
    float* S2        = (float*)(ws + 135168);
    int*   perm      = (int*)(ws + 266240);

    hipMemsetAsync(d_ws, 0, 266240, stream);   // counts + S1 + S2
    tilesort<<<NTILES, 256, 0, stream>>>(bins, perm, tileCount, counts);
    pass    <<<dim3(NTILES, NB), 256, 0, stream>>>(parts, projs, perm, tileCount, S1, S2);
    finalize<<<NB, 256, 0, stream>>>(S1, S2, counts, out);
}